// Round 13
// baseline (566.514 us; speedup 1.0000x reference)
//
#include <hip/hip_runtime.h>
#include <hip/hip_fp16.h>

#define NN 50000
#define NE 800000
#define IN_CH 128
#define HID 256
#define NG 1024
#define BN_EPS 1e-5f
#define NPART 64

using half8   = __attribute__((ext_vector_type(8))) _Float16;
using floatx4 = __attribute__((ext_vector_type(4))) float;

static __device__ inline unsigned short f2h(float f) {
    _Float16 h = (_Float16)f;   // RNE
    return *reinterpret_cast<unsigned short*>(&h);
}
static __device__ inline float h2f(unsigned short u) {
    _Float16 h = *reinterpret_cast<_Float16*>(&u);
    return (float)h;
}

// ========== prep: weight reorders + dst histogram (one kernel) ================
static __device__ inline void reorder_one(const float* __restrict__ W,
                                          unsigned short* __restrict__ Wf, int idx) {
    int jj   = idx & 7;
    int lane = (idx >> 3) & 63;
    int nt   = (idx >> 9) & 15;
    int kc   = idx >> 13;
    int k = kc * 32 + ((lane >> 4) << 3) + jj;
    int n = nt * 16 + (lane & 15);
    Wf[idx] = f2h(W[k * 256 + n]);
}

__global__ void prep_inputs(const float* __restrict__ W_emb,
                            const float* __restrict__ W_conv,
                            const int* __restrict__ dst,
                            unsigned short* __restrict__ wf_emb,
                            unsigned short* __restrict__ wf_conv,
                            int* __restrict__ cnt) {
    const int WE = IN_CH * 256;
    const int WC = 3 * HID * 256;
    int idx = blockIdx.x * blockDim.x + threadIdx.x;
    if (idx < WE) { reorder_one(W_emb, wf_emb, idx); return; }
    int j = idx - WE;
    if (j < WC) {
        int l = j >> 16;          // HID*256 = 65536
        int k = j & 65535;
        reorder_one(W_conv + (size_t)l * HID * HID, wf_conv + (size_t)l * HID * 256, k);
        return;
    }
    j -= WC;
    if (j < NE) atomicAdd(&cnt[dst[j]], 1);
}

// ================= CSR scan =================
__global__ void scan_bsum(const int* __restrict__ cnt, int* __restrict__ bsum) {
    __shared__ int red[256];
    int t = threadIdx.x;
    int i = blockIdx.x * 256 + t;
    red[t] = (i < NN) ? cnt[i] : 0;
    __syncthreads();
    for (int s = 128; s > 0; s >>= 1) {
        if (t < s) red[t] += red[t + s];
        __syncthreads();
    }
    if (t == 0) bsum[blockIdx.x] = red[0];
}

__global__ void scan_offsets(const int* __restrict__ bsum, int* __restrict__ bofs,
                             int* __restrict__ row_ptr) {
    __shared__ int sh[256];
    int t = threadIdx.x;
    sh[t] = (t < 196) ? bsum[t] : 0;
    __syncthreads();
    for (int off = 1; off < 256; off <<= 1) {
        int v = (t >= off) ? sh[t - off] : 0;
        __syncthreads();
        sh[t] += v;
        __syncthreads();
    }
    if (t < 196) bofs[t] = (t == 0) ? 0 : sh[t - 1];
    if (t == 0) row_ptr[NN] = NE;
}

__global__ void scan_emit(const int* __restrict__ cnt, const int* __restrict__ bofs,
                          int* __restrict__ row_ptr, int* __restrict__ cursor) {
    __shared__ int sh[256];
    int t = threadIdx.x;
    int i = blockIdx.x * 256 + t;
    int ci = (i < NN) ? cnt[i] : 0;
    sh[t] = ci;
    __syncthreads();
    for (int off = 1; off < 256; off <<= 1) {
        int v = (t >= off) ? sh[t - off] : 0;
        __syncthreads();
        sh[t] += v;
        __syncthreads();
    }
    if (i < NN) {
        int run = bofs[blockIdx.x] + sh[t] - ci;
        row_ptr[i] = run;
        cursor[i] = run;
    }
}

// pack (src | deg_src<<16): kills the dinv gather in the aggregate
__global__ void csr_fill(const int* __restrict__ src, const int* __restrict__ dst,
                         const int* __restrict__ cnt,
                         int* __restrict__ cursor,
                         unsigned int* __restrict__ edge_packed) {
    int e = blockIdx.x * blockDim.x + threadIdx.x;
    if (e >= NE) return;
    int s = src[e];
    int pos = atomicAdd(&cursor[dst[e]], 1);
    edge_packed[pos] = (unsigned int)s | ((unsigned int)cnt[s] << 16);
}

// ======== embedding GEMM (LDS-free, fp32 A converted in-register, fp16 out) ===
__global__ void gemm_emb(const float* __restrict__ A,
                         const unsigned short* __restrict__ Wf,
                         const float* __restrict__ bias,
                         unsigned short* __restrict__ Ch, int M) {
    const int tid  = threadIdx.x;
    const int lane = tid & 63;
    const int wv   = tid >> 6;
    const int quad = lane >> 4;
    const int l16  = lane & 15;
    const int m0   = blockIdx.x * 64;

    floatx4 acc[4][4] = {};
    int rowA[4];
#pragma unroll
    for (int mt = 0; mt < 4; mt++) {
        int r = m0 + mt * 16 + l16;
        rowA[mt] = (r < M) ? r : M - 1;
    }
    for (int kc = 0; kc < IN_CH / 32; kc++) {
        half8 af[4], bf[4];
#pragma unroll
        for (int mt = 0; mt < 4; mt++) {
            const float* p = &A[(size_t)rowA[mt] * IN_CH + kc * 32 + quad * 8];
            float4 p0 = *(const float4*)p;
            float4 p1 = *(const float4*)(p + 4);
            half8 v;
            v[0] = (_Float16)p0.x; v[1] = (_Float16)p0.y;
            v[2] = (_Float16)p0.z; v[3] = (_Float16)p0.w;
            v[4] = (_Float16)p1.x; v[5] = (_Float16)p1.y;
            v[6] = (_Float16)p1.z; v[7] = (_Float16)p1.w;
            af[mt] = v;
        }
#pragma unroll
        for (int nt = 0; nt < 4; nt++) {
            int ntg = wv * 4 + nt;
            bf[nt] = *(const half8*)&Wf[(size_t)((kc * 16 + ntg) * 64 + lane) * 8];
        }
#pragma unroll
        for (int mt = 0; mt < 4; mt++)
#pragma unroll
            for (int nt = 0; nt < 4; nt++)
                acc[mt][nt] = __builtin_amdgcn_mfma_f32_16x16x32_f16(
                    af[mt], bf[nt], acc[mt][nt], 0, 0, 0);
    }
#pragma unroll
    for (int nt = 0; nt < 4; nt++) {
        int col = wv * 64 + nt * 16 + l16;
        float bb = bias[col];
#pragma unroll
        for (int mt = 0; mt < 4; mt++)
#pragma unroll
            for (int i = 0; i < 4; i++) {
                int row = m0 + mt * 16 + quad * 4 + i;
                if (row < M) Ch[(size_t)row * 256 + col] = f2h(acc[mt][nt][i] + bb);
            }
    }
}

// ===== conv GEMM: h' = t @ W + b (fp16 in/out, fused BN stats) ================
__global__ void gemm_conv(const unsigned short* __restrict__ Ah,
                          const unsigned short* __restrict__ Wf,
                          const float* __restrict__ bias,
                          unsigned short* __restrict__ Ch,
                          float* __restrict__ bpart, int M) {
    const int tid  = threadIdx.x;
    const int lane = tid & 63;
    const int wv   = tid >> 6;
    const int quad = lane >> 4;
    const int l16  = lane & 15;
    const int m0   = blockIdx.x * 64;

    floatx4 acc[4][4] = {};
    int rowA[4];
#pragma unroll
    for (int mt = 0; mt < 4; mt++) {
        int r = m0 + mt * 16 + l16;
        rowA[mt] = (r < M) ? r : M - 1;
    }
    for (int kc = 0; kc < HID / 32; kc++) {
        half8 af[4], bf[4];
#pragma unroll
        for (int mt = 0; mt < 4; mt++)
            af[mt] = *(const half8*)&Ah[(size_t)rowA[mt] * HID + kc * 32 + quad * 8];
#pragma unroll
        for (int nt = 0; nt < 4; nt++) {
            int ntg = wv * 4 + nt;
            bf[nt] = *(const half8*)&Wf[(size_t)((kc * 16 + ntg) * 64 + lane) * 8];
        }
#pragma unroll
        for (int mt = 0; mt < 4; mt++)
#pragma unroll
            for (int nt = 0; nt < 4; nt++)
                acc[mt][nt] = __builtin_amdgcn_mfma_f32_16x16x32_f16(
                    af[mt], bf[nt], acc[mt][nt], 0, 0, 0);
    }

    float sl[4] = {0.f, 0.f, 0.f, 0.f};
    float ql[4] = {0.f, 0.f, 0.f, 0.f};
#pragma unroll
    for (int nt = 0; nt < 4; nt++) {
        int col = wv * 64 + nt * 16 + l16;
        float bb = bias[col];
#pragma unroll
        for (int mt = 0; mt < 4; mt++)
#pragma unroll
            for (int i = 0; i < 4; i++) {
                int row = m0 + mt * 16 + quad * 4 + i;
                if (row < M) {
                    float o = acc[mt][nt][i] + bb;
                    Ch[(size_t)row * 256 + col] = f2h(o);
                    sl[nt] += o; ql[nt] += o * o;
                }
            }
    }

    __shared__ float sred[4][4][64];
    __shared__ float qred[4][4][64];
#pragma unroll
    for (int nt = 0; nt < 4; nt++) {
        sred[wv][quad][nt * 16 + l16] = sl[nt];
        qred[wv][quad][nt * 16 + l16] = ql[nt];
    }
    __syncthreads();
    if (quad == 0) {
        float* pb = bpart + (blockIdx.x & (NPART - 1)) * 512;
#pragma unroll
        for (int k = 0; k < 4; k++) {
            int cl = l16 * 4 + k;
            float s = sred[wv][0][cl] + sred[wv][1][cl] + sred[wv][2][cl] + sred[wv][3][cl];
            float q = qred[wv][0][cl] + qred[wv][1][cl] + qred[wv][2][cl] + qred[wv][3][cl];
            atomicAdd(&pb[wv * 64 + cl], s);
            atomicAdd(&pb[256 + wv * 64 + cl], q);
        }
    }
}

// ====== aggregation: t = Â f(h); packed (src|deg) edges, weight in VALU =======
template <bool AFF>
__global__ void gcn_aggregate16(const ushort4* __restrict__ hh,
                                const int* __restrict__ row_ptr,
                                const unsigned int* __restrict__ edge_packed,
                                const float* __restrict__ scale,
                                const float* __restrict__ shift,
                                ushort4* __restrict__ t_out) {
    const int wv   = threadIdx.x >> 6;
    const int lane = threadIdx.x & 63;
    const int d    = blockIdx.x * 4 + wv;   // NN % 4 == 0
    const int c0   = lane * 4;

    float4 sc, sh;
    if (AFF) {
        sc = *(const float4*)&scale[c0];
        sh = *(const float4*)&shift[c0];
    }
    auto fcvt = [&](ushort4 a) -> float4 {
        float4 v;
        v.x = h2f(a.x); v.y = h2f(a.y); v.z = h2f(a.z); v.w = h2f(a.w);
        if (AFF) {
            v.x = fmaxf(v.x * sc.x + sh.x, 0.f);
            v.y = fmaxf(v.y * sc.y + sh.y, 0.f);
            v.z = fmaxf(v.z * sc.z + sh.z, 0.f);
            v.w = fmaxf(v.w * sc.w + sh.w, 0.f);
        }
        return v;
    };

    const int e0 = row_ptr[d];
    const int e1 = row_ptr[d + 1];
    const float dd  = rsqrtf(1.0f + (float)(e1 - e0));  // dinv_d
    const float slw = dd * dd;

    float4 vd = fcvt(hh[(size_t)d * 64 + lane]);
    float4 acc;
    acc.x = vd.x * slw; acc.y = vd.y * slw; acc.z = vd.z * slw; acc.w = vd.w * slw;

    int e = e0;
    for (; e + 8 <= e1; e += 8) {
        unsigned int p[8]; ushort4 a[8];
#pragma unroll
        for (int i = 0; i < 8; i++) p[i] = edge_packed[e + i];
#pragma unroll
        for (int i = 0; i < 8; i++) a[i] = hh[(size_t)(p[i] & 0xffff) * 64 + lane];
#pragma unroll
        for (int i = 0; i < 8; i++) {
            float w = rsqrtf(1.0f + (float)(p[i] >> 16)) * dd;
            float4 v = fcvt(a[i]);
            acc.x += v.x * w;
            acc.y += v.y * w;
            acc.z += v.z * w;
            acc.w += v.w * w;
        }
    }
    for (; e < e1; e++) {
        unsigned int pe = edge_packed[e];
        float w0 = rsqrtf(1.0f + (float)(pe >> 16)) * dd;
        float4 v = fcvt(hh[(size_t)(pe & 0xffff) * 64 + lane]);
        acc.x += v.x * w0;
        acc.y += v.y * w0;
        acc.z += v.z * w0;
        acc.w += v.w * w0;
    }
    ushort4 p;
    p.x = f2h(acc.x); p.y = f2h(acc.y); p.z = f2h(acc.z); p.w = f2h(acc.w);
    t_out[(size_t)d * 64 + lane] = p;
}

__global__ void bn_finalize_part(const float* __restrict__ bpart,
                                 const float* __restrict__ gamma,
                                 const float* __restrict__ beta,
                                 float* __restrict__ scale, float* __restrict__ shift,
                                 float invM) {
    int c = threadIdx.x;
    float s = 0.f, q = 0.f;
    for (int p = 0; p < NPART; p++) {
        s += bpart[p * 512 + c];
        q += bpart[p * 512 + 256 + c];
    }
    float mu = s * invM;
    float var = q * invM - mu * mu;
    float inv = rsqrtf(var + BN_EPS);
    float sc = inv * gamma[c];
    scale[c] = sc;
    shift[c] = beta[c] - mu * sc;
}

// ================= pooling (fp16 input) =================
__global__ void pool_sum16(const unsigned short* __restrict__ h,
                           const int* __restrict__ batch,
                           const float* __restrict__ scale,
                           const float* __restrict__ shift,
                           float* __restrict__ pooled) {
    int c = threadIdx.x;
    int i0 = blockIdx.x * 64;
    int i1 = (i0 + 64 < NN) ? i0 + 64 : NN;
    float sc = scale[c], sh = shift[c];
    float acc = 0.f;
    int g = batch[i0];
    for (int i = i0; i < i1; i++) {
        int gi = batch[i];
        if (gi != g) {
            atomicAdd(&pooled[g * HID + c], acc);
            acc = 0.f;
            g = gi;
        }
        acc += fmaxf(h2f(h[i * HID + c]) * sc + sh, 0.f);
    }
    atomicAdd(&pooled[g * HID + c], acc);
}

// ====== readout GEMM: z = (pooled/count) @ W1 + b1, fused counts + BN stats ===
__global__ void gemm_f32_stats(const float* __restrict__ A, const float* __restrict__ W,
                               const float* __restrict__ bias,
                               const int* __restrict__ batch,
                               float* __restrict__ C, float* __restrict__ bpart) {
    __shared__ float As[32][32];
    __shared__ int ubs[33];
    __shared__ float invc_sh[32];
    const int tid  = threadIdx.x;
    const int lane = tid & 63;
    const int wv   = tid >> 6;
    const int c0   = lane * 4;
    const int r0   = wv * 8;
    const int m0   = blockIdx.x * 32;   // M = NG = 1024

    if (tid < 33) {
        int gq = m0 + tid - 1;   // upper_bound(batch, gq)
        int lo = 0, hi = NN;
        while (lo < hi) { int m = (lo + hi) >> 1; if (batch[m] <= gq) lo = m + 1; else hi = m; }
        ubs[tid] = lo;
    }
    __syncthreads();
    if (tid < 32) invc_sh[tid] = 1.0f / fmaxf((float)(ubs[tid + 1] - ubs[tid]), 1.0f);
    __syncthreads();

    float invc[4];
#pragma unroll
    for (int i = 0; i < 4; i++) invc[i] = invc_sh[(tid >> 5) + i * 8];

    float acc[8][4];
#pragma unroll
    for (int m = 0; m < 8; m++)
#pragma unroll
        for (int j = 0; j < 4; j++) acc[m][j] = 0.f;

    for (int kc = 0; kc < HID; kc += 32) {
        __syncthreads();
#pragma unroll
        for (int i = 0; i < 4; i++) {
            int r  = (tid >> 5) + i * 8;
            int kk = tid & 31;
            As[r][kk] = A[(size_t)(m0 + r) * 256 + kc + kk] * invc[i];
        }
        __syncthreads();
#pragma unroll
        for (int kk = 0; kk < 32; kk++) {
            const float4 w4 = *(const float4*)&W[(kc + kk) * 256 + c0];
#pragma unroll
            for (int m = 0; m < 8; m++) {
                float a = As[r0 + m][kk];
                acc[m][0] += a * w4.x;
                acc[m][1] += a * w4.y;
                acc[m][2] += a * w4.z;
                acc[m][3] += a * w4.w;
            }
        }
    }

    float4 bb = *(const float4*)&bias[c0];
    float sl[4] = {0.f, 0.f, 0.f, 0.f};
    float ql[4] = {0.f, 0.f, 0.f, 0.f};
#pragma unroll
    for (int m = 0; m < 8; m++) {
        int row = m0 + r0 + m;
        float4 o;
        o.x = acc[m][0] + bb.x;
        o.y = acc[m][1] + bb.y;
        o.z = acc[m][2] + bb.z;
        o.w = acc[m][3] + bb.w;
        *(float4*)&C[(size_t)row * 256 + c0] = o;
        sl[0] += o.x; sl[1] += o.y; sl[2] += o.z; sl[3] += o.w;
        ql[0] += o.x * o.x; ql[1] += o.y * o.y; ql[2] += o.z * o.z; ql[3] += o.w * o.w;
    }

    __shared__ float ls[4][256];
    __shared__ float lq[4][256];
    *(float4*)&ls[wv][c0] = make_float4(sl[0], sl[1], sl[2], sl[3]);
    *(float4*)&lq[wv][c0] = make_float4(ql[0], ql[1], ql[2], ql[3]);
    __syncthreads();
    int c = tid;
    float s = ls[0][c] + ls[1][c] + ls[2][c] + ls[3][c];
    float q = lq[0][c] + lq[1][c] + lq[2][c] + lq[3][c];
    float* pb = bpart + (blockIdx.x & (NPART - 1)) * 512;
    atomicAdd(&pb[c], s);
    atomicAdd(&pb[256 + c], q);
}

// ================= head =================
__global__ void final_out(const float* __restrict__ z, const float* __restrict__ scale,
                          const float* __restrict__ shift, const float* __restrict__ W2,
                          const float* __restrict__ b2, float* __restrict__ out) {
    int g = blockIdx.x;
    int c = threadIdx.x;
    float v = z[g * HID + c] * scale[c] + shift[c];
    v = fmaxf(v, 0.f) * W2[c];
    __shared__ float red[256];
    red[c] = v;
    __syncthreads();
    for (int s = 128; s > 0; s >>= 1) {
        if (c < s) red[c] += red[c + s];
        __syncthreads();
    }
    if (c == 0) out[g] = red[0] + b2[0];
}

// ================= launch =================
extern "C" void kernel_launch(void* const* d_in, const int* in_sizes, int n_in,
                              void* d_out, int out_size, void* d_ws, size_t ws_size,
                              hipStream_t stream) {
    const float* x      = (const float*)d_in[0];
    const int*   ei     = (const int*)d_in[1];
    const int*   batch  = (const int*)d_in[2];
    const float* W_emb  = (const float*)d_in[3];
    const float* b_emb  = (const float*)d_in[4];
    const float* W_conv = (const float*)d_in[5];
    const float* b_conv = (const float*)d_in[6];
    const float* gamma  = (const float*)d_in[7];
    const float* beta   = (const float*)d_in[8];
    const float* W1     = (const float*)d_in[9];
    const float* b1     = (const float*)d_in[10];
    const float* g2     = (const float*)d_in[11];
    const float* bt2    = (const float*)d_in[12];
    const float* W2     = (const float*)d_in[13];
    const float* b2     = (const float*)d_in[14];
    float* out = (float*)d_out;

    const int* src = ei;
    const int* dst = ei + NE;

    char* base = (char*)d_ws;
    size_t off = 0;
    auto take = [&](size_t bytes) {
        char* p = base + off;
        off = (off + bytes + 63) & ~(size_t)63;
        return p;
    };
    unsigned short* bufA = (unsigned short*)take((size_t)NN * 256 * 2);  // fp16 ping
    unsigned short* bufB = (unsigned short*)take((size_t)NN * 256 * 2);  // fp16 pong
    float* scaleshift    = (float*)take(512 * 4);
    int*   row_ptr       = (int*)take((NN + 1) * 4);
    int*   cursor        = (int*)take(NN * 4);
    int*   bsum          = (int*)take(256 * 4);
    int*   bofs          = (int*)take(256 * 4);
    unsigned short* wf_emb  = (unsigned short*)take(IN_CH * 256 * 2);
    unsigned short* wf_conv = (unsigned short*)take(3 * HID * 256 * 2);
    unsigned int* edge_packed = (unsigned int*)take((size_t)NE * 4);
    // --- zero zone (single memset) ---
    char* zero_begin = base + off;
    int*   cnt    = (int*)take(NN * 4);
    float* bpart  = (float*)take(4 * NPART * 512 * 4);
    float* pooled = (float*)take((size_t)NG * HID * 4);
    size_t zero_bytes = (size_t)((base + off) - zero_begin);

    float* scale = scaleshift;
    float* shift = scaleshift + 256;
    float* z     = (float*)bufB;   // bufB dead after last conv GEMM consumed t2

    const int B = 256;
    const int SB = (NN + 255) / 256;          // 196
    const int GB = (NN + 63) / 64;            // 782
    const int PREP = (IN_CH * 256 + 3 * HID * 256 + NE + B - 1) / B;

    hipMemsetAsync(zero_begin, 0, zero_bytes, stream);
    prep_inputs<<<PREP, B, 0, stream>>>(W_emb, W_conv, dst, wf_emb, wf_conv, cnt);

    // ---- CSR build ----
    scan_bsum<<<SB, B, 0, stream>>>(cnt, bsum);
    scan_offsets<<<1, B, 0, stream>>>(bsum, bofs, row_ptr);
    scan_emit<<<SB, B, 0, stream>>>(cnt, bofs, row_ptr, cursor);
    csr_fill<<<(NE + B - 1) / B, B, 0, stream>>>(src, dst, cnt, cursor, edge_packed);

    // ---- embedding: bufA = fp16(x @ W_emb + b_emb) ----
    gemm_emb<<<GB, B, 0, stream>>>(x, wf_emb, b_emb, bufA, NN);

    // ---- conv layers: t = Â f(h) ; h' = t @ W + b (BN stats fused) ----
    gcn_aggregate16<false><<<NN / 4, B, 0, stream>>>(
        (const ushort4*)bufA, row_ptr, edge_packed,
        nullptr, nullptr, (ushort4*)bufB);
    gemm_conv<<<GB, B, 0, stream>>>(bufB, wf_conv, b_conv, bufA, bpart, NN);
    bn_finalize_part<<<1, B, 0, stream>>>(bpart, gamma, beta, scale, shift, 1.0f / NN);

    gcn_aggregate16<true><<<NN / 4, B, 0, stream>>>(
        (const ushort4*)bufA, row_ptr, edge_packed,
        scale, shift, (ushort4*)bufB);
    gemm_conv<<<GB, B, 0, stream>>>(bufB, wf_conv + (size_t)HID * 256, b_conv + HID,
                                    bufA, bpart + (size_t)NPART * 512, NN);
    bn_finalize_part<<<1, B, 0, stream>>>(bpart + (size_t)NPART * 512,
                                          gamma + HID, beta + HID, scale, shift,
                                          1.0f / NN);

    gcn_aggregate16<true><<<NN / 4, B, 0, stream>>>(
        (const ushort4*)bufA, row_ptr, edge_packed,
        scale, shift, (ushort4*)bufB);
    gemm_conv<<<GB, B, 0, stream>>>(bufB, wf_conv + (size_t)2 * HID * 256,
                                    b_conv + 2 * HID, bufA,
                                    bpart + (size_t)2 * NPART * 512, NN);
    bn_finalize_part<<<1, B, 0, stream>>>(bpart + (size_t)2 * NPART * 512,
                                          gamma + 2 * HID, beta + 2 * HID, scale, shift,
                                          1.0f / NN);

    // ---- pool (BN3 affine + relu fused; division folded into readout GEMM) ----
    pool_sum16<<<(NN + 63) / 64, B, 0, stream>>>(bufA, batch, scale, shift, pooled);

    // ---- readout ----
    float* slab3 = bpart + (size_t)3 * NPART * 512;
    gemm_f32_stats<<<NG / 32, B, 0, stream>>>(pooled, W1, b1, batch, z, slab3);
    bn_finalize_part<<<1, B, 0, stream>>>(slab3, g2, bt2, scale, shift, 1.0f / NG);
    final_out<<<NG, B, 0, stream>>>(z, scale, shift, W2, b2, out);
}

// Round 14
// 557.436 us; speedup vs baseline: 1.0163x; 1.0163x over previous
//
#include <hip/hip_runtime.h>
#include <hip/hip_fp16.h>

#define NN 50000
#define NE 800000
#define IN_CH 128
#define HID 256
#define NG 1024
#define BN_EPS 1e-5f
#define NPART 64

using half8   = __attribute__((ext_vector_type(8))) _Float16;
using floatx4 = __attribute__((ext_vector_type(4))) float;

static __device__ inline unsigned short f2h(float f) {
    _Float16 h = (_Float16)f;   // RNE
    return *reinterpret_cast<unsigned short*>(&h);
}
static __device__ inline float h2f(unsigned short u) {
    _Float16 h = *reinterpret_cast<_Float16*>(&u);
    return (float)h;
}

// ========== prep: weight reorders + dst histogram (one kernel) ================
static __device__ inline void reorder_one(const float* __restrict__ W,
                                          unsigned short* __restrict__ Wf, int idx) {
    int jj   = idx & 7;
    int lane = (idx >> 3) & 63;
    int nt   = (idx >> 9) & 15;
    int kc   = idx >> 13;
    int k = kc * 32 + ((lane >> 4) << 3) + jj;
    int n = nt * 16 + (lane & 15);
    Wf[idx] = f2h(W[k * 256 + n]);
}

__global__ void prep_inputs(const float* __restrict__ W_emb,
                            const float* __restrict__ W_conv,
                            const int* __restrict__ dst,
                            unsigned short* __restrict__ wf_emb,
                            unsigned short* __restrict__ wf_conv,
                            int* __restrict__ cnt) {
    const int WE = IN_CH * 256;
    const int WC = 3 * HID * 256;
    int idx = blockIdx.x * blockDim.x + threadIdx.x;
    if (idx < WE) { reorder_one(W_emb, wf_emb, idx); return; }
    int j = idx - WE;
    if (j < WC) {
        int l = j >> 16;          // HID*256 = 65536
        int k = j & 65535;
        reorder_one(W_conv + (size_t)l * HID * HID, wf_conv + (size_t)l * HID * 256, k);
        return;
    }
    j -= WC;
    if (j < NE) atomicAdd(&cnt[dst[j]], 1);
}

// ================= CSR scan =================
__global__ void scan_bsum(const int* __restrict__ cnt, int* __restrict__ bsum) {
    __shared__ int red[256];
    int t = threadIdx.x;
    int i = blockIdx.x * 256 + t;
    red[t] = (i < NN) ? cnt[i] : 0;
    __syncthreads();
    for (int s = 128; s > 0; s >>= 1) {
        if (t < s) red[t] += red[t + s];
        __syncthreads();
    }
    if (t == 0) bsum[blockIdx.x] = red[0];
}

__global__ void scan_offsets(const int* __restrict__ bsum, int* __restrict__ bofs,
                             int* __restrict__ row_ptr) {
    __shared__ int sh[256];
    int t = threadIdx.x;
    sh[t] = (t < 196) ? bsum[t] : 0;
    __syncthreads();
    for (int off = 1; off < 256; off <<= 1) {
        int v = (t >= off) ? sh[t - off] : 0;
        __syncthreads();
        sh[t] += v;
        __syncthreads();
    }
    if (t < 196) bofs[t] = (t == 0) ? 0 : sh[t - 1];
    if (t == 0) row_ptr[NN] = NE;
}

__global__ void scan_emit(const int* __restrict__ cnt, const int* __restrict__ bofs,
                          int* __restrict__ row_ptr, int* __restrict__ cursor,
                          float* __restrict__ dinv) {
    __shared__ int sh[256];
    int t = threadIdx.x;
    int i = blockIdx.x * 256 + t;
    int ci = (i < NN) ? cnt[i] : 0;
    sh[t] = ci;
    __syncthreads();
    for (int off = 1; off < 256; off <<= 1) {
        int v = (t >= off) ? sh[t - off] : 0;
        __syncthreads();
        sh[t] += v;
        __syncthreads();
    }
    if (i < NN) {
        int run = bofs[blockIdx.x] + sh[t] - ci;
        row_ptr[i] = run;
        cursor[i] = run;
        dinv[i] = rsqrtf(1.0f + (float)ci);
    }
}

__global__ void csr_fill(const int* __restrict__ src, const int* __restrict__ dst,
                         int* __restrict__ cursor,
                         unsigned short* __restrict__ src_sorted) {
    int e = blockIdx.x * blockDim.x + threadIdx.x;
    if (e >= NE) return;
    int pos = atomicAdd(&cursor[dst[e]], 1);
    src_sorted[pos] = (unsigned short)src[e];   // NN < 65536
}

// ======== embedding GEMM (LDS-free, fp32 A converted in-register, fp16 out) ===
__global__ void gemm_emb(const float* __restrict__ A,
                         const unsigned short* __restrict__ Wf,
                         const float* __restrict__ bias,
                         unsigned short* __restrict__ Ch, int M) {
    const int tid  = threadIdx.x;
    const int lane = tid & 63;
    const int wv   = tid >> 6;
    const int quad = lane >> 4;
    const int l16  = lane & 15;
    const int m0   = blockIdx.x * 64;

    floatx4 acc[4][4] = {};
    int rowA[4];
#pragma unroll
    for (int mt = 0; mt < 4; mt++) {
        int r = m0 + mt * 16 + l16;
        rowA[mt] = (r < M) ? r : M - 1;
    }
    for (int kc = 0; kc < IN_CH / 32; kc++) {
        half8 af[4], bf[4];
#pragma unroll
        for (int mt = 0; mt < 4; mt++) {
            const float* p = &A[(size_t)rowA[mt] * IN_CH + kc * 32 + quad * 8];
            float4 p0 = *(const float4*)p;
            float4 p1 = *(const float4*)(p + 4);
            half8 v;
            v[0] = (_Float16)p0.x; v[1] = (_Float16)p0.y;
            v[2] = (_Float16)p0.z; v[3] = (_Float16)p0.w;
            v[4] = (_Float16)p1.x; v[5] = (_Float16)p1.y;
            v[6] = (_Float16)p1.z; v[7] = (_Float16)p1.w;
            af[mt] = v;
        }
#pragma unroll
        for (int nt = 0; nt < 4; nt++) {
            int ntg = wv * 4 + nt;
            bf[nt] = *(const half8*)&Wf[(size_t)((kc * 16 + ntg) * 64 + lane) * 8];
        }
#pragma unroll
        for (int mt = 0; mt < 4; mt++)
#pragma unroll
            for (int nt = 0; nt < 4; nt++)
                acc[mt][nt] = __builtin_amdgcn_mfma_f32_16x16x32_f16(
                    af[mt], bf[nt], acc[mt][nt], 0, 0, 0);
    }
#pragma unroll
    for (int nt = 0; nt < 4; nt++) {
        int col = wv * 64 + nt * 16 + l16;
        float bb = bias[col];
#pragma unroll
        for (int mt = 0; mt < 4; mt++)
#pragma unroll
            for (int i = 0; i < 4; i++) {
                int row = m0 + mt * 16 + quad * 4 + i;
                if (row < M) Ch[(size_t)row * 256 + col] = f2h(acc[mt][nt][i] + bb);
            }
    }
}

// ===== conv GEMM: h' = t @ W + b (fp16 in/out, fused BN stats) ================
__global__ void gemm_conv(const unsigned short* __restrict__ Ah,
                          const unsigned short* __restrict__ Wf,
                          const float* __restrict__ bias,
                          unsigned short* __restrict__ Ch,
                          float* __restrict__ bpart, int M) {
    const int tid  = threadIdx.x;
    const int lane = tid & 63;
    const int wv   = tid >> 6;
    const int quad = lane >> 4;
    const int l16  = lane & 15;
    const int m0   = blockIdx.x * 64;

    floatx4 acc[4][4] = {};
    int rowA[4];
#pragma unroll
    for (int mt = 0; mt < 4; mt++) {
        int r = m0 + mt * 16 + l16;
        rowA[mt] = (r < M) ? r : M - 1;
    }
    for (int kc = 0; kc < HID / 32; kc++) {
        half8 af[4], bf[4];
#pragma unroll
        for (int mt = 0; mt < 4; mt++)
            af[mt] = *(const half8*)&Ah[(size_t)rowA[mt] * HID + kc * 32 + quad * 8];
#pragma unroll
        for (int nt = 0; nt < 4; nt++) {
            int ntg = wv * 4 + nt;
            bf[nt] = *(const half8*)&Wf[(size_t)((kc * 16 + ntg) * 64 + lane) * 8];
        }
#pragma unroll
        for (int mt = 0; mt < 4; mt++)
#pragma unroll
            for (int nt = 0; nt < 4; nt++)
                acc[mt][nt] = __builtin_amdgcn_mfma_f32_16x16x32_f16(
                    af[mt], bf[nt], acc[mt][nt], 0, 0, 0);
    }

    float sl[4] = {0.f, 0.f, 0.f, 0.f};
    float ql[4] = {0.f, 0.f, 0.f, 0.f};
#pragma unroll
    for (int nt = 0; nt < 4; nt++) {
        int col = wv * 64 + nt * 16 + l16;
        float bb = bias[col];
#pragma unroll
        for (int mt = 0; mt < 4; mt++)
#pragma unroll
            for (int i = 0; i < 4; i++) {
                int row = m0 + mt * 16 + quad * 4 + i;
                if (row < M) {
                    float o = acc[mt][nt][i] + bb;
                    Ch[(size_t)row * 256 + col] = f2h(o);
                    sl[nt] += o; ql[nt] += o * o;
                }
            }
    }

    __shared__ float sred[4][4][64];
    __shared__ float qred[4][4][64];
#pragma unroll
    for (int nt = 0; nt < 4; nt++) {
        sred[wv][quad][nt * 16 + l16] = sl[nt];
        qred[wv][quad][nt * 16 + l16] = ql[nt];
    }
    __syncthreads();
    if (quad == 0) {
        float* pb = bpart + (blockIdx.x & (NPART - 1)) * 512;
#pragma unroll
        for (int k = 0; k < 4; k++) {
            int cl = l16 * 4 + k;
            float s = sred[wv][0][cl] + sred[wv][1][cl] + sred[wv][2][cl] + sred[wv][3][cl];
            float q = qred[wv][0][cl] + qred[wv][1][cl] + qred[wv][2][cl] + qred[wv][3][cl];
            atomicAdd(&pb[wv * 64 + cl], s);
            atomicAdd(&pb[256 + wv * 64 + cl], q);
        }
    }
}

// ====== aggregation: t = Â f(h); unroll-8 + scalar tail (round-12 proven) =====
template <bool AFF>
__global__ void gcn_aggregate16(const ushort4* __restrict__ hh,
                                const int* __restrict__ row_ptr,
                                const unsigned short* __restrict__ src_sorted,
                                const float* __restrict__ dinv,
                                const float* __restrict__ scale,
                                const float* __restrict__ shift,
                                ushort4* __restrict__ t_out) {
    const int wv   = threadIdx.x >> 6;
    const int lane = threadIdx.x & 63;
    const int d    = blockIdx.x * 4 + wv;   // NN % 4 == 0
    const int c0   = lane * 4;

    float4 sc, sh;
    if (AFF) {
        sc = *(const float4*)&scale[c0];
        sh = *(const float4*)&shift[c0];
    }
    auto fcvt = [&](ushort4 a) -> float4 {
        float4 v;
        v.x = h2f(a.x); v.y = h2f(a.y); v.z = h2f(a.z); v.w = h2f(a.w);
        if (AFF) {
            v.x = fmaxf(v.x * sc.x + sh.x, 0.f);
            v.y = fmaxf(v.y * sc.y + sh.y, 0.f);
            v.z = fmaxf(v.z * sc.z + sh.z, 0.f);
            v.w = fmaxf(v.w * sc.w + sh.w, 0.f);
        }
        return v;
    };

    const int e0 = row_ptr[d];
    const int e1 = row_ptr[d + 1];
    const float dd  = rsqrtf(1.0f + (float)(e1 - e0));  // dinv_d
    const float slw = dd * dd;

    float4 vd = fcvt(hh[(size_t)d * 64 + lane]);
    float4 acc;
    acc.x = vd.x * slw; acc.y = vd.y * slw; acc.z = vd.z * slw; acc.w = vd.w * slw;

    int e = e0;
    for (; e + 8 <= e1; e += 8) {
        int s[8]; ushort4 a[8]; float w[8];
#pragma unroll
        for (int i = 0; i < 8; i++) s[i] = src_sorted[e + i];
#pragma unroll
        for (int i = 0; i < 8; i++) a[i] = hh[(size_t)s[i] * 64 + lane];
#pragma unroll
        for (int i = 0; i < 8; i++) w[i] = dinv[s[i]] * dd;
#pragma unroll
        for (int i = 0; i < 8; i++) {
            float4 v = fcvt(a[i]);
            acc.x += v.x * w[i];
            acc.y += v.y * w[i];
            acc.z += v.z * w[i];
            acc.w += v.w * w[i];
        }
    }
    for (; e < e1; e++) {
        int s0 = src_sorted[e];
        float w0 = dinv[s0] * dd;
        float4 v = fcvt(hh[(size_t)s0 * 64 + lane]);
        acc.x += v.x * w0;
        acc.y += v.y * w0;
        acc.z += v.z * w0;
        acc.w += v.w * w0;
    }
    ushort4 p;
    p.x = f2h(acc.x); p.y = f2h(acc.y); p.z = f2h(acc.z); p.w = f2h(acc.w);
    t_out[(size_t)d * 64 + lane] = p;
}

__global__ void bn_finalize_part(const float* __restrict__ bpart,
                                 const float* __restrict__ gamma,
                                 const float* __restrict__ beta,
                                 float* __restrict__ scale, float* __restrict__ shift,
                                 float invM) {
    int c = threadIdx.x;
    float s = 0.f, q = 0.f;
    for (int p = 0; p < NPART; p++) {
        s += bpart[p * 512 + c];
        q += bpart[p * 512 + 256 + c];
    }
    float mu = s * invM;
    float var = q * invM - mu * mu;
    float inv = rsqrtf(var + BN_EPS);
    float sc = inv * gamma[c];
    scale[c] = sc;
    shift[c] = beta[c] - mu * sc;
}

// ================= pooling (fp16 input) =================
__global__ void pool_sum16(const unsigned short* __restrict__ h,
                           const int* __restrict__ batch,
                           const float* __restrict__ scale,
                           const float* __restrict__ shift,
                           float* __restrict__ pooled) {
    int c = threadIdx.x;
    int i0 = blockIdx.x * 64;
    int i1 = (i0 + 64 < NN) ? i0 + 64 : NN;
    float sc = scale[c], sh = shift[c];
    float acc = 0.f;
    int g = batch[i0];
    for (int i = i0; i < i1; i++) {
        int gi = batch[i];
        if (gi != g) {
            atomicAdd(&pooled[g * HID + c], acc);
            acc = 0.f;
            g = gi;
        }
        acc += fmaxf(h2f(h[i * HID + c]) * sc + sh, 0.f);
    }
    atomicAdd(&pooled[g * HID + c], acc);
}

// ====== readout GEMM: z = (pooled/count) @ W1 + b1, fused counts + BN stats ===
__global__ void gemm_f32_stats(const float* __restrict__ A, const float* __restrict__ W,
                               const float* __restrict__ bias,
                               const int* __restrict__ batch,
                               float* __restrict__ C, float* __restrict__ bpart) {
    __shared__ float As[32][32];
    __shared__ int ubs[33];
    __shared__ float invc_sh[32];
    const int tid  = threadIdx.x;
    const int lane = tid & 63;
    const int wv   = tid >> 6;
    const int c0   = lane * 4;
    const int r0   = wv * 8;
    const int m0   = blockIdx.x * 32;   // M = NG = 1024

    if (tid < 33) {
        int gq = m0 + tid - 1;   // upper_bound(batch, gq)
        int lo = 0, hi = NN;
        while (lo < hi) { int m = (lo + hi) >> 1; if (batch[m] <= gq) lo = m + 1; else hi = m; }
        ubs[tid] = lo;
    }
    __syncthreads();
    if (tid < 32) invc_sh[tid] = 1.0f / fmaxf((float)(ubs[tid + 1] - ubs[tid]), 1.0f);
    __syncthreads();

    float invc[4];
#pragma unroll
    for (int i = 0; i < 4; i++) invc[i] = invc_sh[(tid >> 5) + i * 8];

    float acc[8][4];
#pragma unroll
    for (int m = 0; m < 8; m++)
#pragma unroll
        for (int j = 0; j < 4; j++) acc[m][j] = 0.f;

    for (int kc = 0; kc < HID; kc += 32) {
        __syncthreads();
#pragma unroll
        for (int i = 0; i < 4; i++) {
            int r  = (tid >> 5) + i * 8;
            int kk = tid & 31;
            As[r][kk] = A[(size_t)(m0 + r) * 256 + kc + kk] * invc[i];
        }
        __syncthreads();
#pragma unroll
        for (int kk = 0; kk < 32; kk++) {
            const float4 w4 = *(const float4*)&W[(kc + kk) * 256 + c0];
#pragma unroll
            for (int m = 0; m < 8; m++) {
                float a = As[r0 + m][kk];
                acc[m][0] += a * w4.x;
                acc[m][1] += a * w4.y;
                acc[m][2] += a * w4.z;
                acc[m][3] += a * w4.w;
            }
        }
    }

    float4 bb = *(const float4*)&bias[c0];
    float sl[4] = {0.f, 0.f, 0.f, 0.f};
    float ql[4] = {0.f, 0.f, 0.f, 0.f};
#pragma unroll
    for (int m = 0; m < 8; m++) {
        int row = m0 + r0 + m;
        float4 o;
        o.x = acc[m][0] + bb.x;
        o.y = acc[m][1] + bb.y;
        o.z = acc[m][2] + bb.z;
        o.w = acc[m][3] + bb.w;
        *(float4*)&C[(size_t)row * 256 + c0] = o;
        sl[0] += o.x; sl[1] += o.y; sl[2] += o.z; sl[3] += o.w;
        ql[0] += o.x * o.x; ql[1] += o.y * o.y; ql[2] += o.z * o.z; ql[3] += o.w * o.w;
    }

    __shared__ float ls[4][256];
    __shared__ float lq[4][256];
    *(float4*)&ls[wv][c0] = make_float4(sl[0], sl[1], sl[2], sl[3]);
    *(float4*)&lq[wv][c0] = make_float4(ql[0], ql[1], ql[2], ql[3]);
    __syncthreads();
    int c = tid;
    float s = ls[0][c] + ls[1][c] + ls[2][c] + ls[3][c];
    float q = lq[0][c] + lq[1][c] + lq[2][c] + lq[3][c];
    float* pb = bpart + (blockIdx.x & (NPART - 1)) * 512;
    atomicAdd(&pb[c], s);
    atomicAdd(&pb[256 + c], q);
}

// ================= head =================
__global__ void final_out(const float* __restrict__ z, const float* __restrict__ scale,
                          const float* __restrict__ shift, const float* __restrict__ W2,
                          const float* __restrict__ b2, float* __restrict__ out) {
    int g = blockIdx.x;
    int c = threadIdx.x;
    float v = z[g * HID + c] * scale[c] + shift[c];
    v = fmaxf(v, 0.f) * W2[c];
    __shared__ float red[256];
    red[c] = v;
    __syncthreads();
    for (int s = 128; s > 0; s >>= 1) {
        if (c < s) red[c] += red[c + s];
        __syncthreads();
    }
    if (c == 0) out[g] = red[0] + b2[0];
}

// ================= launch =================
extern "C" void kernel_launch(void* const* d_in, const int* in_sizes, int n_in,
                              void* d_out, int out_size, void* d_ws, size_t ws_size,
                              hipStream_t stream) {
    const float* x      = (const float*)d_in[0];
    const int*   ei     = (const int*)d_in[1];
    const int*   batch  = (const int*)d_in[2];
    const float* W_emb  = (const float*)d_in[3];
    const float* b_emb  = (const float*)d_in[4];
    const float* W_conv = (const float*)d_in[5];
    const float* b_conv = (const float*)d_in[6];
    const float* gamma  = (const float*)d_in[7];
    const float* beta   = (const float*)d_in[8];
    const float* W1     = (const float*)d_in[9];
    const float* b1     = (const float*)d_in[10];
    const float* g2     = (const float*)d_in[11];
    const float* bt2    = (const float*)d_in[12];
    const float* W2     = (const float*)d_in[13];
    const float* b2     = (const float*)d_in[14];
    float* out = (float*)d_out;

    const int* src = ei;
    const int* dst = ei + NE;

    char* base = (char*)d_ws;
    size_t off = 0;
    auto take = [&](size_t bytes) {
        char* p = base + off;
        off = (off + bytes + 63) & ~(size_t)63;
        return p;
    };
    unsigned short* bufA = (unsigned short*)take((size_t)NN * 256 * 2);  // fp16 ping
    unsigned short* bufB = (unsigned short*)take((size_t)NN * 256 * 2);  // fp16 pong
    float* dinv          = (float*)take(NN * 4);
    float* scaleshift    = (float*)take(512 * 4);
    int*   row_ptr       = (int*)take((NN + 1) * 4);
    int*   cursor        = (int*)take(NN * 4);
    int*   bsum          = (int*)take(256 * 4);
    int*   bofs          = (int*)take(256 * 4);
    unsigned short* wf_emb  = (unsigned short*)take(IN_CH * 256 * 2);
    unsigned short* wf_conv = (unsigned short*)take(3 * HID * 256 * 2);
    unsigned short* src_sorted = (unsigned short*)take(NE * 2);
    // --- zero zone (single memset) ---
    char* zero_begin = base + off;
    int*   cnt    = (int*)take(NN * 4);
    float* bpart  = (float*)take(4 * NPART * 512 * 4);
    float* pooled = (float*)take((size_t)NG * HID * 4);
    size_t zero_bytes = (size_t)((base + off) - zero_begin);

    float* scale = scaleshift;
    float* shift = scaleshift + 256;
    float* z     = (float*)bufB;   // bufB dead after last conv GEMM consumed t2

    const int B = 256;
    const int SB = (NN + 255) / 256;          // 196
    const int GB = (NN + 63) / 64;            // 782
    const int PREP = (IN_CH * 256 + 3 * HID * 256 + NE + B - 1) / B;

    hipMemsetAsync(zero_begin, 0, zero_bytes, stream);
    prep_inputs<<<PREP, B, 0, stream>>>(W_emb, W_conv, dst, wf_emb, wf_conv, cnt);

    // ---- CSR build ----
    scan_bsum<<<SB, B, 0, stream>>>(cnt, bsum);
    scan_offsets<<<1, B, 0, stream>>>(bsum, bofs, row_ptr);
    scan_emit<<<SB, B, 0, stream>>>(cnt, bofs, row_ptr, cursor, dinv);
    csr_fill<<<(NE + B - 1) / B, B, 0, stream>>>(src, dst, cursor, src_sorted);

    // ---- embedding: bufA = fp16(x @ W_emb + b_emb) ----
    gemm_emb<<<GB, B, 0, stream>>>(x, wf_emb, b_emb, bufA, NN);

    // ---- conv layers: t = Â f(h) ; h' = t @ W + b (BN stats fused) ----
    gcn_aggregate16<false><<<NN / 4, B, 0, stream>>>(
        (const ushort4*)bufA, row_ptr, src_sorted, dinv,
        nullptr, nullptr, (ushort4*)bufB);
    gemm_conv<<<GB, B, 0, stream>>>(bufB, wf_conv, b_conv, bufA, bpart, NN);
    bn_finalize_part<<<1, B, 0, stream>>>(bpart, gamma, beta, scale, shift, 1.0f / NN);

    gcn_aggregate16<true><<<NN / 4, B, 0, stream>>>(
        (const ushort4*)bufA, row_ptr, src_sorted, dinv,
        scale, shift, (ushort4*)bufB);
    gemm_conv<<<GB, B, 0, stream>>>(bufB, wf_conv + (size_t)HID * 256, b_conv + HID,
                                    bufA, bpart + (size_t)NPART * 512, NN);
    bn_finalize_part<<<1, B, 0, stream>>>(bpart + (size_t)NPART * 512,
                                          gamma + HID, beta + HID, scale, shift,
                                          1.0f / NN);

    gcn_aggregate16<true><<<NN / 4, B, 0, stream>>>(
        (const ushort4*)bufA, row_ptr, src_sorted, dinv,
        scale, shift, (ushort4*)bufB);
    gemm_conv<<<GB, B, 0, stream>>>(bufB, wf_conv + (size_t)2 * HID * 256,
                                    b_conv + 2 * HID, bufA,
                                    bpart + (size_t)2 * NPART * 512, NN);
    bn_finalize_part<<<1, B, 0, stream>>>(bpart + (size_t)2 * NPART * 512,
                                          gamma + 2 * HID, beta + 2 * HID, scale, shift,
                                          1.0f / NN);

    // ---- pool (BN3 affine + relu fused; division folded into readout GEMM) ----
    pool_sum16<<<(NN + 63) / 64, B, 0, stream>>>(bufA, batch, scale, shift, pooled);

    // ---- readout ----
    float* slab3 = bpart + (size_t)3 * NPART * 512;
    gemm_f32_stats<<<NG / 32, B, 0, stream>>>(pooled, W1, b1, batch, z, slab3);
    bn_finalize_part<<<1, B, 0, stream>>>(slab3, g2, bt2, scale, shift, 1.0f / NG);
    final_out<<<NG, B, 0, stream>>>(z, scale, shift, W2, b2, out);
}